// Round 2
// baseline (351.539 us; speedup 1.0000x reference)
//
#include <hip/hip_runtime.h>
#include <hip/hip_bf16.h>
#include <stdint.h>

// MultiHeadCrossAttention: B=4, Ld=1024, Le=2048, D_MODEL=1024, H=8, hd=128
// Pipeline: cvt(f32->bf16, fused) -> gemm Q-proj -> gemm KV-proj (k + v^T) ->
//           flash-attn -> gemm O-proj (f32 out)

#define DM   1024
#define NH   8
#define HD   128
#define LDQ  1024
#define LE   2048
#define NB   4

typedef __attribute__((ext_vector_type(8))) short bf16x8;   // 8 bf16 = 4 VGPR
typedef __attribute__((ext_vector_type(4))) float f32x4;

__device__ __forceinline__ unsigned short f2bf(float f) {
  union { float f; uint32_t u; } v; v.f = f;
  uint32_t u = v.u + 0x7fffu + ((v.u >> 16) & 1u);   // RNE
  return (unsigned short)(u >> 16);
}

__device__ __forceinline__ void gl_lds16(const void* g, void* l) {
  // dest is wave-uniform base; HW adds lane*16. Source is per-lane.
  __builtin_amdgcn_global_load_lds(
      (const __attribute__((address_space(1))) void*)g,
      (__attribute__((address_space(3))) void*)l, 16, 0, 0);
}

// ---------------- fused f32 -> bf16 bulk convert (5 regions, 1 launch) -----
// regions in float4 units: x 1048576 | enc 2097152 | Wq 262144 | Wkv 524288 |
// Wo 262144 ; total 4194304
__global__ __launch_bounds__(256) void cvt_all_kernel(
    const float* __restrict__ s0, const float* __restrict__ s1,
    const float* __restrict__ s2, const float* __restrict__ s3,
    const float* __restrict__ s4,
    unsigned short* __restrict__ d0, unsigned short* __restrict__ d1,
    unsigned short* __restrict__ d2, unsigned short* __restrict__ d3,
    unsigned short* __restrict__ d4) {
  const int total = 4194304;
  int i = blockIdx.x * blockDim.x + threadIdx.x;
  int stride = gridDim.x * blockDim.x;
  for (; i < total; i += stride) {
    const float* src; unsigned short* dst; int off;
    if (i < 1048576)      { src = s0; dst = d0; off = i; }
    else if (i < 3145728) { src = s1; dst = d1; off = i - 1048576; }
    else if (i < 3407872) { src = s2; dst = d2; off = i - 3145728; }
    else if (i < 3932160) { src = s3; dst = d3; off = i - 3407872; }
    else                  { src = s4; dst = d4; off = i - 3932160; }
    float4 v = ((const float4*)src)[off];
    ushort4 o;
    o.x = f2bf(v.x); o.y = f2bf(v.y); o.z = f2bf(v.z); o.w = f2bf(v.w);
    ((ushort4*)dst)[off] = o;
  }
}

// ---------------- GEMM: C[M,N] = A[M,K] * B[N,K]^T + bias ----------------
// 128x128 tile, BK=32, 256 thr (4 waves 2x2), 16x16x32 bf16 MFMA.
// LDS tiles staged via global_load_lds (linear dest) with source pre-swizzle
// swz(o) = o ^ (((o>>6)&3)<<4)  (within 64B rows), reads apply same XOR.
// MODE 0: q-proj  -> out0 = q bf16 [B,H,Ld,hd], *1/sqrt(hd) after bias
// MODE 1: kv-proj -> out0 = k bf16 [B,H,Le,hd]; out1 = v^T bf16 [B,H,hd,Le]
// MODE 2: o-proj  -> outf = f32 [M,N] row-major
template <int MODE>
__global__ __launch_bounds__(256) void gemm_bt(const unsigned short* __restrict__ A,
                                               const unsigned short* __restrict__ B,
                                               const float* __restrict__ bias,
                                               unsigned short* __restrict__ out0,
                                               unsigned short* __restrict__ out1,
                                               float* __restrict__ outf,
                                               int M, int N, int K) {
  __shared__ __align__(16) unsigned short As[2][128 * 32];
  __shared__ __align__(16) unsigned short Bs[2][128 * 32];
  const int tid = threadIdx.x;
  const int wave = tid >> 6, lane = tid & 63;
  const int wr = wave >> 1, wc = wave & 1;
  const int g = lane >> 4, c = lane & 15;
  const int m0 = blockIdx.y * 128, n0 = blockIdx.x * 128;

  f32x4 acc[4][4];
#pragma unroll
  for (int i = 0; i < 4; ++i)
#pragma unroll
    for (int j = 0; j < 4; ++j) acc[i][j] = (f32x4){0.f, 0.f, 0.f, 0.f};

  const unsigned short* Abase = A + (size_t)m0 * K;
  const unsigned short* Bbase = B + (size_t)n0 * K;

  auto stage = [&](int buf, int kt) {
    const unsigned short* at = Abase + kt * 32;
    const unsigned short* bt = Bbase + kt * 32;
#pragma unroll
    for (int j = 0; j < 2; ++j) {
      int chunk = wave * 2 + j;                 // 8 chunks of 1KB per tile
      int o = chunk * 1024 + lane * 16;         // logical byte this lane fills
      int os = o ^ (((o >> 6) & 3) << 4);       // pre-swizzled source byte
      int e = os >> 1;
      int row = e >> 5, col = e & 31;
      gl_lds16(at + row * K + col, (char*)(&As[buf][0]) + chunk * 1024);
      gl_lds16(bt + row * K + col, (char*)(&Bs[buf][0]) + chunk * 1024);
    }
  };

  auto compute = [&](int buf) {
    bf16x8 af[4], bfr[4];
#pragma unroll
    for (int mi = 0; mi < 4; ++mi) {
      int row = wr * 64 + mi * 16 + c;
      int byte = (row * 64 + g * 16) ^ ((row & 3) << 4);
      af[mi] = *(const bf16x8*)((const char*)&As[buf][0] + byte);
    }
#pragma unroll
    for (int ni = 0; ni < 4; ++ni) {
      int row = wc * 64 + ni * 16 + c;
      int byte = (row * 64 + g * 16) ^ ((row & 3) << 4);
      bfr[ni] = *(const bf16x8*)((const char*)&Bs[buf][0] + byte);
    }
#pragma unroll
    for (int mi = 0; mi < 4; ++mi)
#pragma unroll
      for (int ni = 0; ni < 4; ++ni)
        acc[mi][ni] = __builtin_amdgcn_mfma_f32_16x16x32_bf16(af[mi], bfr[ni],
                                                              acc[mi][ni], 0, 0, 0);
  };

  const int NT = K >> 5;
  stage(0, 0);
  __syncthreads();
  int cur = 0;
  for (int t = 0; t < NT; ++t) {
    if (t + 1 < NT) stage(cur ^ 1, t + 1);
    compute(cur);
    __syncthreads();   // drains vmcnt for next tile + all reads of cur done
    cur ^= 1;
  }

  // epilogue: C layout col=lane&15, row=(lane>>4)*4+reg
#pragma unroll
  for (int mi = 0; mi < 4; ++mi) {
#pragma unroll
    for (int ni = 0; ni < 4; ++ni) {
      int n = n0 + wc * 64 + ni * 16 + c;
      float bv = bias[n];
#pragma unroll
      for (int r = 0; r < 4; ++r) {
        int m = m0 + wr * 64 + mi * 16 + g * 4 + r;
        float val = acc[mi][ni][r] + bv;
        if constexpr (MODE == 0) {
          val *= 0.08838834764831845f;  // 1/sqrt(128), pre-applied to q
          int b = m >> 10, ld = m & 1023, h = n >> 7, d = n & 127;
          out0[((size_t)((b * 8 + h) * 1024 + ld)) * 128 + d] = f2bf(val);
        } else if constexpr (MODE == 1) {
          int b = m >> 11, le = m & 2047, h = n >> 8, w2 = n & 255;
          if (w2 < 128)
            out0[((size_t)((b * 8 + h) * 2048 + le)) * 128 + w2] = f2bf(val);
          else
            out1[((size_t)((b * 8 + h) * 128 + (w2 - 128))) * 2048 + le] = f2bf(val);
        } else {
          outf[(size_t)m * 1024 + n] = val;
        }
      }
    }
  }
}

// ---------------- flash attention ----------------
// block = 256 thr (4 waves), one (b,h), QBLK=64 (16 q-rows per wave), KVBLK=64.
// q pre-scaled by 1/sqrt(hd). K tile [64][128] & V^T tile [128][64] staged with
// XOR swizzle (pre-swizzled source); P via padded LDS [16][72] per wave.
__global__ __launch_bounds__(256) void attn_kernel(const unsigned short* __restrict__ q,
                                                   const unsigned short* __restrict__ k,
                                                   const unsigned short* __restrict__ vT,
                                                   const float* __restrict__ mask,
                                                   unsigned short* __restrict__ att) {
  __shared__ __align__(16) unsigned short Qs[64 * 128];
  __shared__ __align__(16) unsigned short Ks[64 * 128];
  __shared__ __align__(16) unsigned short Vs[128 * 64];
  __shared__ __align__(16) unsigned short Ps[4][16 * 72];

  const int tid = threadIdx.x, wave = tid >> 6, lane = tid & 63;
  const int g = lane >> 4, c = lane & 15;
  const int bh = blockIdx.y, b = bh >> 3, h = bh & 7;
  const int q0 = blockIdx.x * 64;

  const unsigned short* qbase = q + (size_t)bh * LDQ * HD + (size_t)q0 * HD;
  const unsigned short* kbase = k + (size_t)bh * LE * HD;
  const unsigned short* vbase = vT + (size_t)bh * HD * LE;
  const float* mbase = mask + ((size_t)b * LDQ + q0) * LE;

  // stage Q once (contiguous 16KB, linear)
#pragma unroll
  for (int j = 0; j < 4; ++j) {
    int chunk = wave * 4 + j;
    int o = chunk * 1024 + lane * 16;
    gl_lds16(qbase + (o >> 1), (char*)Qs + chunk * 1024);
  }
  __syncthreads();

  bf16x8 qf[4];  // wave's 16 q-rows as A-fragments, hoisted to regs
#pragma unroll
  for (int kc = 0; kc < 4; ++kc) {
    int row = wave * 16 + c;
    qf[kc] = *(const bf16x8*)((const char*)Qs + row * 256 + kc * 64 + g * 16);
  }

  float m_run[4], l_run[4];
  f32x4 o_acc[8];
#pragma unroll
  for (int r = 0; r < 4; ++r) { m_run[r] = -1e30f; l_run[r] = 0.f; }
#pragma unroll
  for (int i = 0; i < 8; ++i) o_acc[i] = (f32x4){0.f, 0.f, 0.f, 0.f};

  for (int t = 0; t < LE / 64; ++t) {
    const int kv0 = t * 64;
    // K tile [64 kv][128 d] — contiguous 16KB; swizzle within 256B rows
#pragma unroll
    for (int j = 0; j < 4; ++j) {
      int chunk = wave * 4 + j;
      int o = chunk * 1024 + lane * 16;
      int os = o ^ (((o >> 8) & 7) << 4);
      gl_lds16(kbase + (size_t)kv0 * HD + (os >> 1), (char*)Ks + chunk * 1024);
    }
    // V^T tile [128 d][64 kv] — rows strided in global; swizzle within 128B rows
#pragma unroll
    for (int j = 0; j < 4; ++j) {
      int chunk = wave * 4 + j;
      int o = chunk * 1024 + lane * 16;
      int os = o ^ (((o >> 7) & 7) << 4);
      int e = os >> 1;
      int d = e >> 6, kvo = e & 63;
      gl_lds16(vbase + (size_t)d * LE + kv0 + kvo, (char*)Vs + chunk * 1024);
    }
    __syncthreads();

    // S = Q K^T  (M=16 q, N=64 kv, K=128)
    f32x4 s[4];
#pragma unroll
    for (int n = 0; n < 4; ++n) s[n] = (f32x4){0.f, 0.f, 0.f, 0.f};
#pragma unroll
    for (int kc = 0; kc < 4; ++kc) {
#pragma unroll
      for (int n = 0; n < 4; ++n) {
        int kv = n * 16 + c;
        int byte = (kv * 256 + kc * 64 + g * 16) ^ ((kv & 7) << 4);
        bf16x8 kf = *(const bf16x8*)((const char*)Ks + byte);
        s[n] = __builtin_amdgcn_mfma_f32_16x16x32_bf16(qf[kc], kf, s[n], 0, 0, 0);
      }
    }

    // + mask, online softmax (row = g*4+r, cols = n*16+c; reduce over low 4 lane bits)
    float sv[4][4];
#pragma unroll
    for (int n = 0; n < 4; ++n)
#pragma unroll
      for (int r = 0; r < 4; ++r)
        sv[n][r] = s[n][r] + mbase[(size_t)(wave * 16 + g * 4 + r) * LE + kv0 + n * 16 + c];

    float pm[4];
#pragma unroll
    for (int r = 0; r < 4; ++r)
      pm[r] = fmaxf(fmaxf(sv[0][r], sv[1][r]), fmaxf(sv[2][r], sv[3][r]));
#pragma unroll
    for (int off = 1; off < 16; off <<= 1)
#pragma unroll
      for (int r = 0; r < 4; ++r) pm[r] = fmaxf(pm[r], __shfl_xor(pm[r], off));

    float mn[4], sc[4];
#pragma unroll
    for (int r = 0; r < 4; ++r) {
      mn[r] = fmaxf(m_run[r], pm[r]);
      sc[r] = __expf(m_run[r] - mn[r]);
      m_run[r] = mn[r];
    }
    float p[4][4], ps[4];
#pragma unroll
    for (int n = 0; n < 4; ++n)
#pragma unroll
      for (int r = 0; r < 4; ++r) p[n][r] = __expf(sv[n][r] - mn[r]);
#pragma unroll
    for (int r = 0; r < 4; ++r) ps[r] = p[0][r] + p[1][r] + p[2][r] + p[3][r];
#pragma unroll
    for (int off = 1; off < 16; off <<= 1)
#pragma unroll
      for (int r = 0; r < 4; ++r) ps[r] += __shfl_xor(ps[r], off);
#pragma unroll
    for (int r = 0; r < 4; ++r) l_run[r] = l_run[r] * sc[r] + ps[r];
#pragma unroll
    for (int i = 0; i < 8; ++i)
#pragma unroll
      for (int r = 0; r < 4; ++r) o_acc[i][r] *= sc[r];

    // P -> LDS (bf16, padded rows: 72 elems = 144B, keeps 16B alignment)
#pragma unroll
    for (int n = 0; n < 4; ++n)
#pragma unroll
      for (int r = 0; r < 4; ++r)
        Ps[wave][(g * 4 + r) * 72 + n * 16 + c] = f2bf(p[n][r]);
    asm volatile("s_waitcnt lgkmcnt(0)" ::: "memory");
    __builtin_amdgcn_sched_barrier(0);

    // O += P V   (A = P [16 q x 64 kv], B = V^T fragments)
#pragma unroll
    for (int kc2 = 0; kc2 < 2; ++kc2) {
      bf16x8 pa = *(const bf16x8*)((const char*)&Ps[wave][0] + c * 144 + kc2 * 64 + g * 16);
#pragma unroll
      for (int dn = 0; dn < 8; ++dn) {
        int d = dn * 16 + c;
        int byte = (d * 128 + kc2 * 64 + g * 16) ^ ((d & 7) << 4);
        bf16x8 vf = *(const bf16x8*)((const char*)Vs + byte);
        o_acc[dn] = __builtin_amdgcn_mfma_f32_16x16x32_bf16(pa, vf, o_acc[dn], 0, 0, 0);
      }
    }
    __syncthreads();  // protect Ks/Vs before next stage
  }

  // normalize + store att[B,Ld,H*hd] (bf16)
#pragma unroll
  for (int r = 0; r < 4; ++r) l_run[r] = 1.0f / l_run[r];
#pragma unroll
  for (int dn = 0; dn < 8; ++dn)
#pragma unroll
    for (int r = 0; r < 4; ++r) {
      int qrow = q0 + wave * 16 + g * 4 + r;
      att[((size_t)(b * LDQ) + qrow) * DM + h * HD + dn * 16 + c] =
          f2bf(o_acc[dn][r] * l_run[r]);
    }
}

// ---------------- launcher ----------------
extern "C" void kernel_launch(void* const* d_in, const int* in_sizes, int n_in,
                              void* d_out, int out_size, void* d_ws, size_t ws_size,
                              hipStream_t stream) {
  const float* x    = (const float*)d_in[0];
  const float* enc  = (const float*)d_in[1];
  const float* mask = (const float*)d_in[2];
  const float* Wkv  = (const float*)d_in[3];
  const float* bkv  = (const float*)d_in[4];
  const float* Wq   = (const float*)d_in[5];
  const float* bq   = (const float*)d_in[6];
  const float* Wo   = (const float*)d_in[7];
  const float* bo   = (const float*)d_in[8];
  float* out = (float*)d_out;

  char* ws = (char*)d_ws;
  unsigned short* x_bf   = (unsigned short*)ws; ws += (size_t)4096 * 1024 * 2;
  unsigned short* enc_bf = (unsigned short*)ws; ws += (size_t)8192 * 1024 * 2;
  unsigned short* wq_bf  = (unsigned short*)ws; ws += (size_t)1024 * 1024 * 2;
  unsigned short* wkv_bf = (unsigned short*)ws; ws += (size_t)2048 * 1024 * 2;
  unsigned short* wo_bf  = (unsigned short*)ws; ws += (size_t)1024 * 1024 * 2;
  unsigned short* q_bf   = (unsigned short*)ws; ws += (size_t)4096 * 1024 * 2;  // [B,H,Ld,hd]
  unsigned short* k_bf   = (unsigned short*)ws; ws += (size_t)8192 * 1024 * 2;  // [B,H,Le,hd]
  unsigned short* vT_bf  = (unsigned short*)ws; ws += (size_t)8192 * 1024 * 2;  // [B,H,hd,Le]
  unsigned short* att_bf = (unsigned short*)ws; ws += (size_t)4096 * 1024 * 2;  // [B,Ld,DM]

  // fused convert: x, enc, Wq, Wkv, Wo  (biases stay f32)
  cvt_all_kernel<<<2048, 256, 0, stream>>>(x, enc, Wq, Wkv, Wo,
                                           x_bf, enc_bf, wq_bf, wkv_bf, wo_bf);

  // q-proj: [4096,1024] = x @ Wq^T
  gemm_bt<0><<<dim3(8, 32), 256, 0, stream>>>(x_bf, wq_bf, bq, q_bf, nullptr, nullptr,
                                              4096, 1024, 1024);
  // kv-proj: [8192,2048] = enc @ Wkv^T  -> k + v^T
  gemm_bt<1><<<dim3(16, 64), 256, 0, stream>>>(enc_bf, wkv_bf, bkv, k_bf, vT_bf, nullptr,
                                               8192, 2048, 1024);
  // attention
  attn_kernel<<<dim3(16, 32), 256, 0, stream>>>(q_bf, k_bf, vT_bf, mask, att_bf);
  // o-proj: f32 out
  gemm_bt<2><<<dim3(8, 32), 256, 0, stream>>>(att_bf, wo_bf, bo, nullptr, nullptr, out,
                                              4096, 1024, 1024);
}